// Round 7
// baseline (1176.493 us; speedup 1.0000x reference)
//
#include <hip/hip_runtime.h>
#include <hip/hip_cooperative_groups.h>
#include <math.h>

namespace cg = cooperative_groups;

#define DH 128

typedef short short8 __attribute__((ext_vector_type(8)));
typedef float f32x4 __attribute__((ext_vector_type(4)));

__device__ __forceinline__ unsigned short f2bu(float f) {
  unsigned int u = __builtin_bit_cast(unsigned int, f);
  unsigned int r = (u + 0x7fffu + ((u >> 16) & 1u)) >> 16;
  return (unsigned short)r;
}
__device__ __forceinline__ float blo(unsigned int u) {
  return __builtin_bit_cast(float, u << 16);
}
__device__ __forceinline__ float bhi(unsigned int u) {
  return __builtin_bit_cast(float, u & 0xffff0000u);
}
__device__ __forceinline__ unsigned int packb2(float a, float b) {
  return (unsigned int)f2bu(a) | ((unsigned int)f2bu(b) << 16);
}

struct P {
  const float* x; const int* erow; const int* ecol;
  const float* w_in; const float* b_in;
  const float* w_gcn; const float* b_gcn;
  const float* w_nc1; const float* b_nc1; const float* w_nc2; const float* b_nc2;
  const float* w_oc1; const float* b_oc1; const float* w_oc2; const float* b_oc2;
  float* out_node; float* out_orig; float* out_err; float* h;
  unsigned short* xwb; unsigned short* hb;
  unsigned short* w_inT; unsigned short* w_gcnT;
  unsigned short* w_nc1T; unsigned short* w_oc1T;
  float* dinv; int* cnt; int* rowptr; int* bsum; int* rank; int* csr;
  int N; int E;
};

// ---- per-wave GEMM tile: 16 rows x 128 cols, full K in regs, no LDS ----
template <int K, bool AF, int MODE>
__device__ __forceinline__ void gemm_wave(const void* A_, const unsigned short* WT,
                                          const float* bias, const float* dscale,
                                          float* Cf, unsigned short* Cb, int n,
                                          int gw, int GW, int lr, int lg) {
  for (int r0 = gw * 16; r0 < n; r0 += GW * 16) {
    f32x4 acc[8] = {};
#pragma unroll
    for (int kk = 0; kk < K / 32; kk++) {
      const int koff = kk * 32 + lg * 8;
      int row = r0 + lr;
      row = row < n ? row : n - 1;
      short8 a;
      if (AF) {
        const float* Af = (const float*)A_;
        float4 pq = *(const float4*)&Af[(size_t)row * K + koff];
        float4 q = *(const float4*)&Af[(size_t)row * K + koff + 4];
        a[0] = (short)f2bu(pq.x); a[1] = (short)f2bu(pq.y);
        a[2] = (short)f2bu(pq.z); a[3] = (short)f2bu(pq.w);
        a[4] = (short)f2bu(q.x);  a[5] = (short)f2bu(q.y);
        a[6] = (short)f2bu(q.z);  a[7] = (short)f2bu(q.w);
      } else {
        a = *(const short8*)&((const unsigned short*)A_)[(size_t)row * K + koff];
      }
#pragma unroll
      for (int nb = 0; nb < 8; nb++) {
        short8 bfr = *(const short8*)&WT[(size_t)(nb * 16 + lr) * K + koff];
        acc[nb] = __builtin_amdgcn_mfma_f32_16x16x32_bf16(a, bfr, acc[nb], 0, 0, 0);
      }
    }
    if (MODE == 0) {
#pragma unroll
      for (int i = 0; i < 4; i++) {
        int row = r0 + lg * 4 + i;
        if (row < n) {
          float sc = dscale[row];
#pragma unroll
          for (int nb = 0; nb < 8; nb++)
            Cb[(size_t)row * DH + nb * 16 + lr] = f2bu(acc[nb][i] * sc);
        }
      }
    } else {
      float bcol[8];
#pragma unroll
      for (int nb = 0; nb < 8; nb++) bcol[nb] = bias[nb * 16 + lr];
#pragma unroll
      for (int i = 0; i < 4; i++) {
        int row = r0 + lg * 4 + i;
        if (row < n) {
#pragma unroll
          for (int nb = 0; nb < 8; nb++) {
            float v = fmaxf(acc[nb][i] + bcol[nb], 0.f);
            Cf[(size_t)row * DH + nb * 16 + lr] = v;
            Cb[(size_t)row * DH + nb * 16 + lr] = f2bu(v);
          }
        }
      }
    }
  }
}

// ---- per-wave aggregation: one node per wave-iteration ----
__device__ __forceinline__ void agg_wave(const uint2* xwb2, const float* dinv,
                                         const int* rowptr, const int* csr,
                                         const float* bias, float* h, uint2* hb2,
                                         int n, int gw, int GW, int lane) {
  const int half = lane >> 5;
  const int cidx = lane & 31;
  for (int node = gw; node < n; node += GW) {
    const float self = dinv[node];
    float a0, a1, a2, a3;
    if (half == 0) {
      uint2 su = xwb2[(size_t)node * 32 + cidx];
      a0 = blo(su.x); a1 = bhi(su.x); a2 = blo(su.y); a3 = bhi(su.y);
    } else {
      a0 = a1 = a2 = a3 = 0.f;
    }
    const int beg = rowptr[node], end = rowptr[node + 1];
    int j = beg;
    for (; j + 16 <= end; j += 16) {
      int s[8];
#pragma unroll
      for (int k = 0; k < 8; k++) s[k] = csr[j + 2 * k + half];
      uint2 u[8];
#pragma unroll
      for (int k = 0; k < 8; k++) u[k] = xwb2[(size_t)s[k] * 32 + cidx];
#pragma unroll
      for (int k = 0; k < 8; k++) {
        a0 += blo(u[k].x); a1 += bhi(u[k].x);
        a2 += blo(u[k].y); a3 += bhi(u[k].y);
      }
    }
    for (; j + 8 <= end; j += 8) {
      int s0 = csr[j + half], s1 = csr[j + 2 + half];
      int s2 = csr[j + 4 + half], s3 = csr[j + 6 + half];
      uint2 u0 = xwb2[(size_t)s0 * 32 + cidx];
      uint2 u1 = xwb2[(size_t)s1 * 32 + cidx];
      uint2 u2 = xwb2[(size_t)s2 * 32 + cidx];
      uint2 u3 = xwb2[(size_t)s3 * 32 + cidx];
      a0 += blo(u0.x); a1 += bhi(u0.x); a2 += blo(u0.y); a3 += bhi(u0.y);
      a0 += blo(u1.x); a1 += bhi(u1.x); a2 += blo(u1.y); a3 += bhi(u1.y);
      a0 += blo(u2.x); a1 += bhi(u2.x); a2 += blo(u2.y); a3 += bhi(u2.y);
      a0 += blo(u3.x); a1 += bhi(u3.x); a2 += blo(u3.y); a3 += bhi(u3.y);
    }
    for (; j < end; j += 2) {
      int jj = j + half;
      if (jj < end) {
        int s = csr[jj];
        uint2 u = xwb2[(size_t)s * 32 + cidx];
        a0 += blo(u.x); a1 += bhi(u.x); a2 += blo(u.y); a3 += bhi(u.y);
      }
    }
    a0 += __shfl_xor(a0, 32);
    a1 += __shfl_xor(a1, 32);
    a2 += __shfl_xor(a2, 32);
    a3 += __shfl_xor(a3, 32);
    if (half == 0) {
      const float4 bv = *(const float4*)&bias[cidx * 4];
      const float4 hv = *(const float4*)&h[(size_t)node * DH + cidx * 4];
      float r0 = fmaxf(hv.x + self * a0 + bv.x, 0.f);
      float r1 = fmaxf(hv.y + self * a1 + bv.y, 0.f);
      float r2 = fmaxf(hv.z + self * a2 + bv.z, 0.f);
      float r3 = fmaxf(hv.w + self * a3 + bv.w, 0.f);
      *(float4*)&h[(size_t)node * DH + cidx * 4] = make_float4(r0, r1, r2, r3);
      hb2[(size_t)node * 32 + cidx] = make_uint2(packb2(r0, r1), packb2(r2, r3));
    }
  }
}

// ---- per-wave dual MLP heads: 16 rows per wave-iteration ----
__device__ __forceinline__ void heads_wave(
    const unsigned short* hb,
    const unsigned short* w1T_a, const float* b1_a, const float* w2_a, const float* b2_a,
    const unsigned short* w1T_b, const float* b1_b, const float* w2_b, const float* b2_b,
    float* out_a, float* out_b, int n, int gw, int GW, int lr, int lg) {
  for (int r0 = gw * 16; r0 < n; r0 += GW * 16) {
#pragma unroll
    for (int head = 0; head < 2; head++) {
      const unsigned short* W1T = head ? w1T_b : w1T_a;
      const float* b1 = head ? b1_b : b1_a;
      const float* w2 = head ? w2_b : w2_a;
      const float b2 = head ? b2_b[0] : b2_a[0];
      float* out = head ? out_b : out_a;
      f32x4 acc[8] = {};
#pragma unroll
      for (int kk = 0; kk < 4; kk++) {
        const int koff = kk * 32 + lg * 8;
        int row = r0 + lr;
        row = row < n ? row : n - 1;
        short8 a = *(const short8*)&hb[(size_t)row * DH + koff];
#pragma unroll
        for (int nb = 0; nb < 8; nb++) {
          short8 bfr = *(const short8*)&W1T[(size_t)(nb * 16 + lr) * DH + koff];
          acc[nb] = __builtin_amdgcn_mfma_f32_16x16x32_bf16(a, bfr, acc[nb], 0, 0, 0);
        }
      }
      float b1v[8], w2v[8];
#pragma unroll
      for (int nb = 0; nb < 8; nb++) {
        b1v[nb] = b1[nb * 16 + lr];
        w2v[nb] = w2[nb * 16 + lr];
      }
#pragma unroll
      for (int i = 0; i < 4; i++) {
        float s = 0.f;
#pragma unroll
        for (int nb = 0; nb < 8; nb++)
          s += fmaxf(acc[nb][i] + b1v[nb], 0.f) * w2v[nb];
        s += __shfl_xor(s, 1);
        s += __shfl_xor(s, 2);
        s += __shfl_xor(s, 4);
        s += __shfl_xor(s, 8);
        int row = r0 + lg * 4 + i;
        if (lr == 0 && row < n) out[row] = 1.f / (1.f + __expf(-(s + b2)));
      }
    }
  }
}

// ---------------- the mega kernel ----------------

__global__ __launch_bounds__(256, 4) void gcn_mega(P p) {
  cg::grid_group gg = cg::this_grid();
  const int t = threadIdx.x;
  const int b = blockIdx.x;
  const int G = gridDim.x;
  const int tid = b * 256 + t;
  const int NT = G * 256;
  const int lane = t & 63, w = t >> 6;
  const int lr = lane & 15, lg = lane >> 4;
  const int gw = b * 4 + w, GW = G * 4;
  const int N = p.N, E = p.E;

  __shared__ int wsum[4];
  __shared__ int pre[65];

  // P0: weight transposes + zero cnt + zero out_err
  const int prepTot = 114688 + 5 * N;
  for (int idx = tid; idx < prepTot; idx += NT) {
    if (idx < 32768) {
      int k = idx >> 7, c = idx & 127;
      p.w_inT[c * 256 + k] = f2bu(p.w_in[idx]);
    } else if (idx < 81920) {
      int sub = idx - 32768, off = sub & 16383;
      int k = off >> 7, c = off & 127;
      p.w_gcnT[(sub >> 14) * 16384 + c * 128 + k] = f2bu(p.w_gcn[sub]);
    } else if (idx < 98304) {
      int off = idx - 81920, k = off >> 7, c = off & 127;
      p.w_nc1T[c * 128 + k] = f2bu(p.w_nc1[off]);
    } else if (idx < 114688) {
      int off = idx - 98304, k = off >> 7, c = off & 127;
      p.w_oc1T[c * 128 + k] = f2bu(p.w_oc1[off]);
    } else if (idx < 114688 + N) {
      p.cnt[idx - 114688] = 0;
    } else {
      p.out_err[idx - 114688 - N] = 0.f;
    }
  }
  gg.sync();

  // P1: count (+rank)
  for (int i = tid; i < E; i += NT) p.rank[i] = atomicAdd(&p.cnt[p.ecol[i]], 1);
  gg.sync();

  // P2: per-1024-chunk exclusive scan + dinv
  const int nchunks = (N + 1023) >> 10;
  for (int c = b; c < nchunks; c += G) {
    int i0 = (c << 10) + t * 4;
    int v[4], tsum = 0;
#pragma unroll
    for (int k = 0; k < 4; k++) {
      int i = i0 + k;
      v[k] = (i < N) ? p.cnt[i] : 0;
      tsum += v[k];
    }
    int s = tsum;
#pragma unroll
    for (int d = 1; d < 64; d <<= 1) {
      int u = __shfl_up(s, d);
      if (lane >= d) s += u;
    }
    if (lane == 63) wsum[w] = s;
    __syncthreads();
    int wpre = 0;
    for (int k = 0; k < w; k++) wpre += wsum[k];
    int ex = wpre + s - tsum;
#pragma unroll
    for (int k = 0; k < 4; k++) {
      int i = i0 + k;
      if (i < N) {
        p.rowptr[i] = ex;
        p.dinv[i] = rsqrtf((float)(v[k] + 1));
        ex += v[k];
      }
    }
    if (t == 0) p.bsum[c] = wsum[0] + wsum[1] + wsum[2] + wsum[3];
    __syncthreads();
  }
  gg.sync();

  // P3: add chunk prefixes
  if (t < 64) {
    int v = (t < nchunks) ? p.bsum[t] : 0;
    int s = v;
#pragma unroll
    for (int d = 1; d < 64; d <<= 1) {
      int u = __shfl_up(s, d);
      if (lane >= d) s += u;
    }
    pre[t] = s - v;
    if (t == 63) pre[64] = s;
  }
  __syncthreads();
  for (int i = tid; i < N; i += NT) p.rowptr[i] += pre[i >> 10];
  if (b == 0 && t == 0) p.rowptr[N] = pre[64];
  gg.sync();

  // P4: fill CSR
  for (int i = tid; i < E; i += NT) p.csr[p.rowptr[p.ecol[i]] + p.rank[i]] = p.erow[i];
  gg.sync();

  // P5: input projection h = relu(x @ w_in + b_in); hb = bf16(h)
  gemm_wave<256, true, 1>(p.x, p.w_inT, p.b_in, nullptr, p.h, p.hb, N, gw, GW, lr, lg);
  gg.sync();

  // P6: 3 GCN layers
  for (int l = 0; l < 3; l++) {
    gemm_wave<128, false, 0>(p.hb, p.w_gcnT + l * 16384, nullptr, p.dinv,
                             nullptr, p.xwb, N, gw, GW, lr, lg);
    gg.sync();
    agg_wave((const uint2*)p.xwb, p.dinv, p.rowptr, p.csr, p.b_gcn + l * DH,
             p.h, (uint2*)p.hb, N, gw, GW, lane);
    gg.sync();
  }

  // P7: fused heads
  heads_wave(p.hb, p.w_nc1T, p.b_nc1, p.w_nc2, p.b_nc2,
             p.w_oc1T, p.b_oc1, p.w_oc2, p.b_oc2,
             p.out_node, p.out_orig, N, gw, GW, lr, lg);
}

// ---------------- launch ----------------

extern "C" void kernel_launch(void* const* d_in, const int* in_sizes, int n_in,
                              void* d_out, int out_size, void* d_ws, size_t ws_size,
                              hipStream_t stream) {
  const float* x     = (const float*)d_in[0];
  const int*   ei    = (const int*)d_in[1];

  const int N = in_sizes[0] / 256;  // 50000
  const int E = in_sizes[1] / 2;    // 600000

  float* out = (float*)d_out;

  // workspace carve
  unsigned short* xwb = (unsigned short*)d_ws;            // N*128 bf16
  unsigned short* hb  = xwb + (size_t)N * DH;             // N*128 bf16
  unsigned short* w_inT  = hb + (size_t)N * DH;           // 128 x 256
  unsigned short* w_gcnT = w_inT + 128 * 256;             // 3 x 128 x 128
  unsigned short* w_nc1T = w_gcnT + 3 * 128 * 128;
  unsigned short* w_oc1T = w_nc1T + 128 * 128;
  float* dinv = (float*)(w_oc1T + 128 * 128);             // N
  int* cnt    = (int*)(dinv + N);                         // N
  int* rowptr = cnt + N;                                  // N+1
  int* bsum   = rowptr + N + 1;                           // 64
  int* rank   = bsum + 64;                                // E
  int* csr    = rank + E;                                 // E

  P p;
  p.x = x; p.erow = ei; p.ecol = ei + E;
  p.w_in  = (const float*)d_in[2];  p.b_in  = (const float*)d_in[3];
  p.w_gcn = (const float*)d_in[4];  p.b_gcn = (const float*)d_in[5];
  p.w_nc1 = (const float*)d_in[6];  p.b_nc1 = (const float*)d_in[7];
  p.w_nc2 = (const float*)d_in[8];  p.b_nc2 = (const float*)d_in[9];
  p.w_oc1 = (const float*)d_in[10]; p.b_oc1 = (const float*)d_in[11];
  p.w_oc2 = (const float*)d_in[12]; p.b_oc2 = (const float*)d_in[13];
  p.out_node = out;
  p.out_orig = out + N;
  p.out_err  = out + 2 * (size_t)N;
  p.h        = out + 6 * (size_t)N;
  p.xwb = xwb; p.hb = hb;
  p.w_inT = w_inT; p.w_gcnT = w_gcnT; p.w_nc1T = w_nc1T; p.w_oc1T = w_oc1T;
  p.dinv = dinv; p.cnt = cnt; p.rowptr = rowptr; p.bsum = bsum;
  p.rank = rank; p.csr = csr;
  p.N = N; p.E = E;

  int maxB = 0;
  hipOccupancyMaxActiveBlocksPerMultiprocessor(&maxB, gcn_mega, 256, 0);
  int G = maxB * 256;           // 256 CUs on MI355X
  if (G > 2048) G = 2048;
  if (G < 256) G = 256;

  void* kp[] = {&p};
  hipLaunchCooperativeKernel((void*)gcn_mega, dim3(G), dim3(256), kp, 0, stream);
}

// Round 8
// 239.791 us; speedup vs baseline: 4.9063x; 4.9063x over previous
//
#include <hip/hip_runtime.h>
#include <math.h>

#define DH 128

typedef short short8 __attribute__((ext_vector_type(8)));
typedef float f32x4 __attribute__((ext_vector_type(4)));

__device__ __forceinline__ unsigned short f2bu(float f) {
  unsigned int u = __builtin_bit_cast(unsigned int, f);
  unsigned int r = (u + 0x7fffu + ((u >> 16) & 1u)) >> 16;
  return (unsigned short)r;
}
__device__ __forceinline__ float blo(unsigned int u) {
  return __builtin_bit_cast(float, u << 16);
}
__device__ __forceinline__ float bhi(unsigned int u) {
  return __builtin_bit_cast(float, u & 0xffff0000u);
}
__device__ __forceinline__ unsigned int packb2(float a, float b) {
  return (unsigned int)f2bu(a) | ((unsigned int)f2bu(b) << 16);
}

// ---------------- prep: weight transposes (fp32 [K][128] -> bf16 [128][K]) + zeroing ----------------

__global__ __launch_bounds__(256) void prep_kernel(
    const float* __restrict__ w_in, const float* __restrict__ w_gcn,
    const float* __restrict__ w_nc1, const float* __restrict__ w_oc1,
    unsigned short* __restrict__ w_inT, unsigned short* __restrict__ w_gcnT,
    unsigned short* __restrict__ w_nc1T, unsigned short* __restrict__ w_oc1T,
    int* __restrict__ cnt, float* __restrict__ out_err, int n) {
  int idx = blockIdx.x * 256 + threadIdx.x;
  if (idx < 32768) {  // w_in: K=256
    int k = idx >> 7, c = idx & 127;
    w_inT[c * 256 + k] = f2bu(w_in[idx]);
  } else if (idx < 81920) {  // 3 gcn layers
    int sub = idx - 32768;
    int off = sub & 16383;
    int k = off >> 7, c = off & 127;
    w_gcnT[(sub >> 14) * 16384 + c * 128 + k] = f2bu(w_gcn[sub]);
  } else if (idx < 98304) {
    int off = idx - 81920;
    int k = off >> 7, c = off & 127;
    w_nc1T[c * 128 + k] = f2bu(w_nc1[off]);
  } else if (idx < 114688) {
    int off = idx - 98304;
    int k = off >> 7, c = off & 127;
    w_oc1T[c * 128 + k] = f2bu(w_oc1[off]);
  } else if (idx < 114688 + n) {
    cnt[idx - 114688] = 0;
  } else if (idx < 114688 + 5 * n) {
    out_err[idx - 114688 - n] = 0.f;
  }
}

// ---------------- scans ----------------

__global__ __launch_bounds__(1024) void scan1_kernel(const int* __restrict__ cnt,
                                                     int* __restrict__ rowptr,
                                                     float* __restrict__ dinv,
                                                     int* __restrict__ bsum, int n) {
  __shared__ int wsum[16];
  const int t = threadIdx.x;
  const int lane = t & 63, wid = t >> 6;
  const int i = blockIdx.x * 1024 + t;
  int v = (i < n) ? cnt[i] : 0;
  int s = v;
#pragma unroll
  for (int d = 1; d < 64; d <<= 1) {
    int u = __shfl_up(s, d);
    if (lane >= d) s += u;
  }
  if (lane == 63) wsum[wid] = s;
  __syncthreads();
  if (t < 16) {
    int ws = wsum[t];
#pragma unroll
    for (int d = 1; d < 16; d <<= 1) {
      int u = __shfl_up(ws, d);
      if (t >= d) ws += u;
    }
    wsum[t] = ws;
  }
  __syncthreads();
  if (i < n) {
    rowptr[i] = (wid ? wsum[wid - 1] : 0) + s - v;
    dinv[i] = rsqrtf((float)(v + 1));
  }
  if (t == 0) bsum[blockIdx.x] = wsum[15];
}

__global__ __launch_bounds__(256) void scan3_kernel(int* __restrict__ rowptr,
                                                    const int* __restrict__ bsum,
                                                    int n, int nb) {
  __shared__ int pre[64];
  int total = 0;
  if (threadIdx.x < 64) {
    int v = (threadIdx.x < nb) ? bsum[threadIdx.x] : 0;
    int s = v;
#pragma unroll
    for (int d = 1; d < 64; d <<= 1) {
      int u = __shfl_up(s, d);
      if ((threadIdx.x & 63) >= d) s += u;
    }
    pre[threadIdx.x] = s - v;  // exclusive
    total = s;
  }
  __syncthreads();
  int i = blockIdx.x * 256 + threadIdx.x;
  if (i < n) rowptr[i] += pre[i >> 10];
  if (blockIdx.x == 0 && threadIdx.x == 63) rowptr[n] = total;
}

// ---------------- shared GEMM tile body: 128 rows x 128 cols per block ----------------
// 4 waves (2x2); each wave 64 rows x 64 cols via 4x4 16x16 frags.
// MODE 0: store bf16 scaled by dscale[row]. MODE 1: bias+relu, store fp32 + bf16.

template <int K, bool A_FP32, int MODE>
__device__ __forceinline__ void gemm_tile(const void* __restrict__ A_,
                                          const unsigned short* __restrict__ WT,
                                          const float* __restrict__ bias,
                                          const float* __restrict__ dscale,
                                          float* __restrict__ Cf,
                                          unsigned short* __restrict__ Cb, int n,
                                          int bid, int t) {
  const int lane = t & 63;
  const int w = t >> 6;
  const int wr = w >> 1, wc = w & 1;
  const int lr = lane & 15, lg = lane >> 4;
  const int r_base = bid * 128 + wr * 64;
  const int c_base = wc * 64;

  f32x4 acc[4][4] = {};

#pragma unroll
  for (int kk = 0; kk < K / 32; kk++) {
    const int koff = kk * 32 + lg * 8;
    short8 a[4], b[4];
#pragma unroll
    for (int m = 0; m < 4; m++) {
      int row = r_base + m * 16 + lr;
      row = row < n ? row : n - 1;
      if (A_FP32) {
        const float* Af = (const float*)A_;
        float4 p = *(const float4*)&Af[(size_t)row * K + koff];
        float4 q = *(const float4*)&Af[(size_t)row * K + koff + 4];
        short8 av;
        av[0] = (short)f2bu(p.x); av[1] = (short)f2bu(p.y);
        av[2] = (short)f2bu(p.z); av[3] = (short)f2bu(p.w);
        av[4] = (short)f2bu(q.x); av[5] = (short)f2bu(q.y);
        av[6] = (short)f2bu(q.z); av[7] = (short)f2bu(q.w);
        a[m] = av;
      } else {
        const unsigned short* Ab = (const unsigned short*)A_;
        a[m] = *(const short8*)&Ab[(size_t)row * K + koff];
      }
    }
#pragma unroll
    for (int nb = 0; nb < 4; nb++) {
      int col = c_base + nb * 16 + lr;
      b[nb] = *(const short8*)&WT[(size_t)col * K + koff];
    }
#pragma unroll
    for (int m = 0; m < 4; m++)
#pragma unroll
      for (int nb = 0; nb < 4; nb++)
        acc[m][nb] = __builtin_amdgcn_mfma_f32_16x16x32_bf16(a[m], b[nb], acc[m][nb], 0, 0, 0);
  }

  float bcol[4];
  if (MODE != 0) {
#pragma unroll
    for (int nb = 0; nb < 4; nb++) bcol[nb] = bias[c_base + nb * 16 + lr];
  }

#pragma unroll
  for (int m = 0; m < 4; m++) {
#pragma unroll
    for (int i = 0; i < 4; i++) {
      int row = r_base + m * 16 + lg * 4 + i;
      if (row < n) {
        float sc = (MODE == 0) ? dscale[row] : 0.f;
#pragma unroll
        for (int nb = 0; nb < 4; nb++) {
          int col = c_base + nb * 16 + lr;
          float v = acc[m][nb][i];
          if (MODE == 0) {
            Cb[(size_t)row * DH + col] = f2bu(v * sc);
          } else {
            v = fmaxf(v + bcol[nb], 0.f);
            Cf[(size_t)row * DH + col] = v;
            Cb[(size_t)row * DH + col] = f2bu(v);
          }
        }
      }
    }
  }
}

// ---------------- fused: CSR count (blocks [0,CB)) || input GEMM (blocks [CB,..)) ----------------

__global__ __launch_bounds__(256) void count_ingemm_kernel(
    const int* __restrict__ ecol, int* __restrict__ cnt, int* __restrict__ rank, int e,
    const float* __restrict__ x, const unsigned short* __restrict__ w_inT,
    const float* __restrict__ b_in, float* __restrict__ h,
    unsigned short* __restrict__ hb, int n, int CB) {
  if ((int)blockIdx.x < CB) {
    const int stride = CB * 256;
    for (int i = blockIdx.x * 256 + threadIdx.x; i < e; i += stride)
      rank[i] = atomicAdd(&cnt[ecol[i]], 1);
  } else {
    gemm_tile<256, true, 1>(x, w_inT, b_in, nullptr, h, hb, n,
                            blockIdx.x - CB, threadIdx.x);
  }
}

// ---------------- fused: CSR fill (blocks [0,FB)) || layer-0 GEMM (blocks [FB,..)) ----------------

__global__ __launch_bounds__(256) void fill_gemm_kernel(
    const int* __restrict__ row, const int* __restrict__ col,
    const int* __restrict__ rowptr, const int* __restrict__ rank,
    int* __restrict__ csr, int e,
    const unsigned short* __restrict__ hb, const unsigned short* __restrict__ wT,
    const float* __restrict__ dscale, unsigned short* __restrict__ xwb, int n, int FB) {
  if ((int)blockIdx.x < FB) {
    const int stride = FB * 256;
    for (int i = blockIdx.x * 256 + threadIdx.x; i < e; i += stride)
      csr[rowptr[col[i]] + rank[i]] = row[i];
  } else {
    gemm_tile<128, false, 0>(hb, wT, nullptr, dscale, nullptr, xwb, n,
                             blockIdx.x - FB, threadIdx.x);
  }
}

// ---------------- standalone GEMM ----------------

template <int K, bool A_FP32, int MODE>
__global__ __launch_bounds__(256) void gemm_kernel(const void* __restrict__ A_,
                                                   const unsigned short* __restrict__ WT,
                                                   const float* __restrict__ bias,
                                                   const float* __restrict__ dscale,
                                                   float* __restrict__ Cf,
                                                   unsigned short* __restrict__ Cb, int n) {
  gemm_tile<K, A_FP32, MODE>(A_, WT, bias, dscale, Cf, Cb, n, blockIdx.x, threadIdx.x);
}

// ---------------- aggregation: h = relu(h + self * sum(xwb') + b) ----------------
// xwb' rows pre-scaled by dinv[src]; pure gather-add; 16-edge (8/half-wave) pipeline.

__global__ __launch_bounds__(256) void agg_kernel(const uint2* __restrict__ xwb2,
                                                  const float* __restrict__ dinv,
                                                  const int* __restrict__ rowptr,
                                                  const int* __restrict__ csr,
                                                  const float* __restrict__ bias,
                                                  float* __restrict__ h,
                                                  uint2* __restrict__ hb2, int n) {
  const int node = blockIdx.x * 4 + (threadIdx.x >> 6);
  if (node >= n) return;
  const int lane = threadIdx.x & 63;
  const int half = lane >> 5;
  const int cidx = lane & 31;
  const float self = dinv[node];

  float a0, a1, a2, a3;
  if (half == 0) {  // self loop counted once
    uint2 su = xwb2[(size_t)node * 32 + cidx];
    a0 = blo(su.x); a1 = bhi(su.x);
    a2 = blo(su.y); a3 = bhi(su.y);
  } else {
    a0 = a1 = a2 = a3 = 0.f;
  }

  const int beg = rowptr[node], end = rowptr[node + 1];
  int j = beg;
  for (; j + 16 <= end; j += 16) {
    int s[8];
#pragma unroll
    for (int k = 0; k < 8; k++) s[k] = csr[j + 2 * k + half];
    uint2 u[8];
#pragma unroll
    for (int k = 0; k < 8; k++) u[k] = xwb2[(size_t)s[k] * 32 + cidx];
#pragma unroll
    for (int k = 0; k < 8; k++) {
      a0 += blo(u[k].x); a1 += bhi(u[k].x);
      a2 += blo(u[k].y); a3 += bhi(u[k].y);
    }
  }
  for (; j + 8 <= end; j += 8) {
    int s0 = csr[j + half], s1 = csr[j + 2 + half];
    int s2 = csr[j + 4 + half], s3 = csr[j + 6 + half];
    uint2 u0 = xwb2[(size_t)s0 * 32 + cidx];
    uint2 u1 = xwb2[(size_t)s1 * 32 + cidx];
    uint2 u2 = xwb2[(size_t)s2 * 32 + cidx];
    uint2 u3 = xwb2[(size_t)s3 * 32 + cidx];
    a0 += blo(u0.x); a1 += bhi(u0.x); a2 += blo(u0.y); a3 += bhi(u0.y);
    a0 += blo(u1.x); a1 += bhi(u1.x); a2 += blo(u1.y); a3 += bhi(u1.y);
    a0 += blo(u2.x); a1 += bhi(u2.x); a2 += blo(u2.y); a3 += bhi(u2.y);
    a0 += blo(u3.x); a1 += bhi(u3.x); a2 += blo(u3.y); a3 += bhi(u3.y);
  }
  for (; j < end; j += 2) {
    int jj = j + half;
    if (jj < end) {
      int s = csr[jj];
      uint2 u = xwb2[(size_t)s * 32 + cidx];
      a0 += blo(u.x); a1 += bhi(u.x); a2 += blo(u.y); a3 += bhi(u.y);
    }
  }

  a0 += __shfl_xor(a0, 32);
  a1 += __shfl_xor(a1, 32);
  a2 += __shfl_xor(a2, 32);
  a3 += __shfl_xor(a3, 32);

  if (half == 0) {
    const float4 bv = *(const float4*)&bias[cidx * 4];
    const float4 hv = *(const float4*)&h[(size_t)node * DH + cidx * 4];
    float r0 = fmaxf(hv.x + self * a0 + bv.x, 0.f);
    float r1 = fmaxf(hv.y + self * a1 + bv.y, 0.f);
    float r2 = fmaxf(hv.z + self * a2 + bv.z, 0.f);
    float r3 = fmaxf(hv.w + self * a3 + bv.w, 0.f);
    *(float4*)&h[(size_t)node * DH + cidx * 4] = make_float4(r0, r1, r2, r3);
    hb2[(size_t)node * 32 + cidx] = make_uint2(packb2(r0, r1), packb2(r2, r3));
  }
}

// ---------------- fused dual MLP head (128-row block, 32 rows/wave) ----------------

__global__ __launch_bounds__(256) void heads_kernel(
    const unsigned short* __restrict__ hb,
    const unsigned short* __restrict__ w1T_a, const float* __restrict__ b1_a,
    const float* __restrict__ w2_a, const float* __restrict__ b2_a,
    const unsigned short* __restrict__ w1T_b, const float* __restrict__ b1_b,
    const float* __restrict__ w2_b, const float* __restrict__ b2_b,
    float* __restrict__ out_a, float* __restrict__ out_b, int n) {
  const int t = threadIdx.x;
  const int lane = t & 63;
  const int w = t >> 6;
  const int lr = lane & 15, lg = lane >> 4;
  const int r_base = blockIdx.x * 128 + w * 32;

#pragma unroll
  for (int head = 0; head < 2; head++) {
    const unsigned short* W1T = head ? w1T_b : w1T_a;
    const float* b1 = head ? b1_b : b1_a;
    const float* w2 = head ? w2_b : w2_a;
    const float b2 = head ? b2_b[0] : b2_a[0];
    float* out = head ? out_b : out_a;

    f32x4 acc[2][8] = {};
#pragma unroll
    for (int kk = 0; kk < 4; kk++) {
      const int koff = kk * 32 + lg * 8;
      short8 a[2];
#pragma unroll
      for (int m = 0; m < 2; m++) {
        int row = r_base + m * 16 + lr;
        row = row < n ? row : n - 1;
        a[m] = *(const short8*)&hb[(size_t)row * DH + koff];
      }
#pragma unroll
      for (int nb = 0; nb < 8; nb++) {
        short8 b = *(const short8*)&W1T[(size_t)(nb * 16 + lr) * DH + koff];
#pragma unroll
        for (int m = 0; m < 2; m++)
          acc[m][nb] = __builtin_amdgcn_mfma_f32_16x16x32_bf16(a[m], b, acc[m][nb], 0, 0, 0);
      }
    }

    float b1v[8], w2v[8];
#pragma unroll
    for (int nb = 0; nb < 8; nb++) {
      b1v[nb] = b1[nb * 16 + lr];
      w2v[nb] = w2[nb * 16 + lr];
    }

#pragma unroll
    for (int m = 0; m < 2; m++) {
#pragma unroll
      for (int i = 0; i < 4; i++) {
        float s = 0.f;
#pragma unroll
        for (int nb = 0; nb < 8; nb++)
          s += fmaxf(acc[m][nb][i] + b1v[nb], 0.f) * w2v[nb];
        s += __shfl_xor(s, 1);
        s += __shfl_xor(s, 2);
        s += __shfl_xor(s, 4);
        s += __shfl_xor(s, 8);
        int row = r_base + m * 16 + lg * 4 + i;
        if (lr == 0 && row < n) out[row] = 1.f / (1.f + __expf(-(s + b2)));
      }
    }
  }
}

// ---------------- launch ----------------

extern "C" void kernel_launch(void* const* d_in, const int* in_sizes, int n_in,
                              void* d_out, int out_size, void* d_ws, size_t ws_size,
                              hipStream_t stream) {
  const float* x     = (const float*)d_in[0];
  const int*   ei    = (const int*)d_in[1];
  const float* w_in  = (const float*)d_in[2];
  const float* b_in  = (const float*)d_in[3];
  const float* w_gcn = (const float*)d_in[4];
  const float* b_gcn = (const float*)d_in[5];
  const float* w_nc1 = (const float*)d_in[6];
  const float* b_nc1 = (const float*)d_in[7];
  const float* w_nc2 = (const float*)d_in[8];
  const float* b_nc2 = (const float*)d_in[9];
  const float* w_oc1 = (const float*)d_in[10];
  const float* b_oc1 = (const float*)d_in[11];
  const float* w_oc2 = (const float*)d_in[12];
  const float* b_oc2 = (const float*)d_in[13];

  const int N = in_sizes[0] / 256;  // 50000
  const int E = in_sizes[1] / 2;    // 600000
  const int* erow = ei;
  const int* ecol = ei + E;

  float* out      = (float*)d_out;
  float* out_node = out;
  float* out_orig = out + N;
  float* out_err  = out + 2 * (size_t)N;
  float* h        = out + 6 * (size_t)N;  // final h lives directly in d_out

  // workspace carve
  unsigned short* xwb = (unsigned short*)d_ws;            // N*128 bf16
  unsigned short* hb  = xwb + (size_t)N * DH;             // N*128 bf16
  unsigned short* w_inT  = hb + (size_t)N * DH;           // 128 x 256
  unsigned short* w_gcnT = w_inT + 128 * 256;             // 3 x 128 x 128
  unsigned short* w_nc1T = w_gcnT + 3 * 128 * 128;
  unsigned short* w_oc1T = w_nc1T + 128 * 128;
  float* dinv = (float*)(w_oc1T + 128 * 128);             // N
  int* cnt    = (int*)(dinv + N);                         // N
  int* rowptr = cnt + N;                                  // N+1
  int* bsum   = rowptr + N + 1;                           // 64
  int* rank   = bsum + 64;                                // E
  int* csr    = rank + E;                                 // E

  prep_kernel<<<(114688 + 5 * N + 255) / 256, 256, 0, stream>>>(
      w_in, w_gcn, w_nc1, w_oc1, w_inT, w_gcnT, w_nc1T, w_oc1T, cnt, out_err, N);

  const int gb = (N + 127) / 128;  // 391
  const int CB = 160, FB = 160;

  // fused: count+rank || input projection (h = relu(x @ w_in + b_in); hb = bf16(h))
  count_ingemm_kernel<<<CB + gb, 256, 0, stream>>>(ecol, cnt, rank, E,
                                                   x, w_inT, b_in, h, hb, N, CB);

  const int nb1 = (N + 1023) / 1024;
  scan1_kernel<<<nb1, 1024, 0, stream>>>(cnt, rowptr, dinv, bsum, N);
  scan3_kernel<<<(N + 255) / 256, 256, 0, stream>>>(rowptr, bsum, N, nb1);

  // fused: CSR fill || layer-0 GEMM (xwb = dinv * (hb @ W0))
  fill_gemm_kernel<<<FB + gb, 256, 0, stream>>>(erow, ecol, rowptr, rank, csr, E,
                                                hb, w_gcnT, dinv, xwb, N, FB);
  agg_kernel<<<(N + 3) / 4, 256, 0, stream>>>((const uint2*)xwb, dinv, rowptr, csr,
                                              b_gcn, h, (uint2*)hb, N);

  // layers 1,2
  for (int l = 1; l < 3; l++) {
    gemm_kernel<128, false, 0><<<gb, 256, 0, stream>>>(hb, w_gcnT + (size_t)l * DH * DH,
                                                       nullptr, dinv, nullptr, xwb, N);
    agg_kernel<<<(N + 3) / 4, 256, 0, stream>>>((const uint2*)xwb, dinv, rowptr, csr,
                                                b_gcn + (size_t)l * DH, h,
                                                (uint2*)hb, N);
  }
  // fused heads
  heads_kernel<<<gb, 256, 0, stream>>>(hb, w_nc1T, b_nc1, w_nc2, b_nc2,
                                       w_oc1T, b_oc1, w_oc2, b_oc2,
                                       out_node, out_orig, N);
}

// Round 9
// 233.420 us; speedup vs baseline: 5.0402x; 1.0273x over previous
//
#include <hip/hip_runtime.h>
#include <math.h>

#define DH 128

typedef short short8 __attribute__((ext_vector_type(8)));
typedef float f32x4 __attribute__((ext_vector_type(4)));

__device__ __forceinline__ unsigned short f2bu(float f) {
  unsigned int u = __builtin_bit_cast(unsigned int, f);
  unsigned int r = (u + 0x7fffu + ((u >> 16) & 1u)) >> 16;
  return (unsigned short)r;
}
__device__ __forceinline__ float blo(unsigned int u) {
  return __builtin_bit_cast(float, u << 16);
}
__device__ __forceinline__ float bhi(unsigned int u) {
  return __builtin_bit_cast(float, u & 0xffff0000u);
}
__device__ __forceinline__ unsigned int packb2(float a, float b) {
  return (unsigned int)f2bu(a) | ((unsigned int)f2bu(b) << 16);
}

// ---------------- prep: weight transposes (fp32 [K][128] -> bf16 [128][K]) + zeroing ----------------

__global__ __launch_bounds__(256) void prep_kernel(
    const float* __restrict__ w_in, const float* __restrict__ w_gcn,
    const float* __restrict__ w_nc1, const float* __restrict__ w_oc1,
    unsigned short* __restrict__ w_inT, unsigned short* __restrict__ w_gcnT,
    unsigned short* __restrict__ w_nc1T, unsigned short* __restrict__ w_oc1T,
    int* __restrict__ cnt, float* __restrict__ out_err, int n) {
  int idx = blockIdx.x * 256 + threadIdx.x;
  if (idx < 32768) {  // w_in: K=256
    int k = idx >> 7, c = idx & 127;
    w_inT[c * 256 + k] = f2bu(w_in[idx]);
  } else if (idx < 81920) {  // 3 gcn layers
    int sub = idx - 32768;
    int off = sub & 16383;
    int k = off >> 7, c = off & 127;
    w_gcnT[(sub >> 14) * 16384 + c * 128 + k] = f2bu(w_gcn[sub]);
  } else if (idx < 98304) {
    int off = idx - 81920;
    int k = off >> 7, c = off & 127;
    w_nc1T[c * 128 + k] = f2bu(w_nc1[off]);
  } else if (idx < 114688) {
    int off = idx - 98304;
    int k = off >> 7, c = off & 127;
    w_oc1T[c * 128 + k] = f2bu(w_oc1[off]);
  } else if (idx < 114688 + n) {
    cnt[idx - 114688] = 0;
  } else if (idx < 114688 + 5 * n) {
    out_err[idx - 114688 - n] = 0.f;
  }
}

// ---------------- scans ----------------

__global__ __launch_bounds__(1024) void scan1_kernel(const int* __restrict__ cnt,
                                                     int* __restrict__ rowptr,
                                                     float* __restrict__ dinv,
                                                     int* __restrict__ bsum, int n) {
  __shared__ int wsum[16];
  const int t = threadIdx.x;
  const int lane = t & 63, wid = t >> 6;
  const int i = blockIdx.x * 1024 + t;
  int v = (i < n) ? cnt[i] : 0;
  int s = v;
#pragma unroll
  for (int d = 1; d < 64; d <<= 1) {
    int u = __shfl_up(s, d);
    if (lane >= d) s += u;
  }
  if (lane == 63) wsum[wid] = s;
  __syncthreads();
  if (t < 16) {
    int ws = wsum[t];
#pragma unroll
    for (int d = 1; d < 16; d <<= 1) {
      int u = __shfl_up(ws, d);
      if (t >= d) ws += u;
    }
    wsum[t] = ws;
  }
  __syncthreads();
  if (i < n) {
    rowptr[i] = (wid ? wsum[wid - 1] : 0) + s - v;
    dinv[i] = rsqrtf((float)(v + 1));
  }
  if (t == 0) bsum[blockIdx.x] = wsum[15];
}

__global__ __launch_bounds__(256) void scan3_kernel(int* __restrict__ rowptr,
                                                    const int* __restrict__ bsum,
                                                    int n, int nb) {
  __shared__ int pre[64];
  int total = 0;
  if (threadIdx.x < 64) {
    int v = (threadIdx.x < nb) ? bsum[threadIdx.x] : 0;
    int s = v;
#pragma unroll
    for (int d = 1; d < 64; d <<= 1) {
      int u = __shfl_up(s, d);
      if ((threadIdx.x & 63) >= d) s += u;
    }
    pre[threadIdx.x] = s - v;  // exclusive
    total = s;
  }
  __syncthreads();
  int i = blockIdx.x * 256 + threadIdx.x;
  if (i < n) rowptr[i] += pre[i >> 10];
  if (blockIdx.x == 0 && threadIdx.x == 63) rowptr[n] = total;
}

// ---------------- shared GEMM tile body: 128 rows x 128 cols per block ----------------
// 4 waves (2x2); each wave 64 rows x 64 cols via 4x4 16x16 frags.
// MODE 0: store bf16 scaled by dscale[row]. MODE 1: bias+relu, store bf16 only.

template <int K, bool A_FP32, int MODE>
__device__ __forceinline__ void gemm_tile(const void* __restrict__ A_,
                                          const unsigned short* __restrict__ WT,
                                          const float* __restrict__ bias,
                                          const float* __restrict__ dscale,
                                          unsigned short* __restrict__ Cb, int n,
                                          int bid, int t) {
  const int lane = t & 63;
  const int w = t >> 6;
  const int wr = w >> 1, wc = w & 1;
  const int lr = lane & 15, lg = lane >> 4;
  const int r_base = bid * 128 + wr * 64;
  const int c_base = wc * 64;

  f32x4 acc[4][4] = {};

#pragma unroll
  for (int kk = 0; kk < K / 32; kk++) {
    const int koff = kk * 32 + lg * 8;
    short8 a[4], b[4];
#pragma unroll
    for (int m = 0; m < 4; m++) {
      int row = r_base + m * 16 + lr;
      row = row < n ? row : n - 1;
      if (A_FP32) {
        const float* Af = (const float*)A_;
        float4 p = *(const float4*)&Af[(size_t)row * K + koff];
        float4 q = *(const float4*)&Af[(size_t)row * K + koff + 4];
        short8 av;
        av[0] = (short)f2bu(p.x); av[1] = (short)f2bu(p.y);
        av[2] = (short)f2bu(p.z); av[3] = (short)f2bu(p.w);
        av[4] = (short)f2bu(q.x); av[5] = (short)f2bu(q.y);
        av[6] = (short)f2bu(q.z); av[7] = (short)f2bu(q.w);
        a[m] = av;
      } else {
        const unsigned short* Ab = (const unsigned short*)A_;
        a[m] = *(const short8*)&Ab[(size_t)row * K + koff];
      }
    }
#pragma unroll
    for (int nb = 0; nb < 4; nb++) {
      int col = c_base + nb * 16 + lr;
      b[nb] = *(const short8*)&WT[(size_t)col * K + koff];
    }
#pragma unroll
    for (int m = 0; m < 4; m++)
#pragma unroll
      for (int nb = 0; nb < 4; nb++)
        acc[m][nb] = __builtin_amdgcn_mfma_f32_16x16x32_bf16(a[m], b[nb], acc[m][nb], 0, 0, 0);
  }

  float bcol[4];
  if (MODE != 0) {
#pragma unroll
    for (int nb = 0; nb < 4; nb++) bcol[nb] = bias[c_base + nb * 16 + lr];
  }

#pragma unroll
  for (int m = 0; m < 4; m++) {
#pragma unroll
    for (int i = 0; i < 4; i++) {
      int row = r_base + m * 16 + lg * 4 + i;
      if (row < n) {
        float sc = (MODE == 0) ? dscale[row] : 0.f;
#pragma unroll
        for (int nb = 0; nb < 4; nb++) {
          int col = c_base + nb * 16 + lr;
          float v = acc[m][nb][i];
          if (MODE == 0) {
            Cb[(size_t)row * DH + col] = f2bu(v * sc);
          } else {
            v = fmaxf(v + bcol[nb], 0.f);
            Cb[(size_t)row * DH + col] = f2bu(v);
          }
        }
      }
    }
  }
}

// ---------------- fused: CSR count (blocks [0,CB)) || input GEMM (blocks [CB,..)) ----------------

__global__ __launch_bounds__(256) void count_ingemm_kernel(
    const int* __restrict__ ecol, int* __restrict__ cnt, int* __restrict__ rank, int e,
    const float* __restrict__ x, const unsigned short* __restrict__ w_inT,
    const float* __restrict__ b_in, unsigned short* __restrict__ hb, int n, int CB) {
  if ((int)blockIdx.x < CB) {
    const int stride = CB * 256;
    for (int i = blockIdx.x * 256 + threadIdx.x; i < e; i += stride)
      rank[i] = atomicAdd(&cnt[ecol[i]], 1);
  } else {
    gemm_tile<256, true, 1>(x, w_inT, b_in, nullptr, hb, n,
                            blockIdx.x - CB, threadIdx.x);
  }
}

// ---------------- fused: CSR fill (blocks [0,FB)) || layer-0 GEMM (blocks [FB,..)) ----------------

__global__ __launch_bounds__(256) void fill_gemm_kernel(
    const int* __restrict__ row, const int* __restrict__ col,
    const int* __restrict__ rowptr, const int* __restrict__ rank,
    int* __restrict__ csr, int e,
    const unsigned short* __restrict__ hb, const unsigned short* __restrict__ wT,
    const float* __restrict__ dscale, unsigned short* __restrict__ xwb, int n, int FB) {
  if ((int)blockIdx.x < FB) {
    const int stride = FB * 256;
    for (int i = blockIdx.x * 256 + threadIdx.x; i < e; i += stride)
      csr[rowptr[col[i]] + rank[i]] = row[i];
  } else {
    gemm_tile<128, false, 0>(hb, wT, nullptr, dscale, xwb, n,
                             blockIdx.x - FB, threadIdx.x);
  }
}

// ---------------- standalone GEMM ----------------

template <int K, bool A_FP32, int MODE>
__global__ __launch_bounds__(256) void gemm_kernel(const void* __restrict__ A_,
                                                   const unsigned short* __restrict__ WT,
                                                   const float* __restrict__ bias,
                                                   const float* __restrict__ dscale,
                                                   unsigned short* __restrict__ Cb, int n) {
  gemm_tile<K, A_FP32, MODE>(A_, WT, bias, dscale, Cb, n, blockIdx.x, threadIdx.x);
}

// ---------------- aggregation: h = relu(hb + self * sum(xwb') + b) ----------------
// Residual read from bf16 hb2; writes bf16 hb2; if hout != nullptr also writes fp32.

__global__ __launch_bounds__(256) void agg_kernel(const uint2* __restrict__ xwb2,
                                                  const float* __restrict__ dinv,
                                                  const int* __restrict__ rowptr,
                                                  const int* __restrict__ csr,
                                                  const float* __restrict__ bias,
                                                  uint2* __restrict__ hb2,
                                                  float* __restrict__ hout, int n) {
  const int node = blockIdx.x * 4 + (threadIdx.x >> 6);
  if (node >= n) return;
  const int lane = threadIdx.x & 63;
  const int half = lane >> 5;
  const int cidx = lane & 31;
  const float self = dinv[node];

  float a0, a1, a2, a3;
  if (half == 0) {  // self loop counted once
    uint2 su = xwb2[(size_t)node * 32 + cidx];
    a0 = blo(su.x); a1 = bhi(su.x);
    a2 = blo(su.y); a3 = bhi(su.y);
  } else {
    a0 = a1 = a2 = a3 = 0.f;
  }

  const int beg = rowptr[node], end = rowptr[node + 1];
  int j = beg;
  for (; j + 16 <= end; j += 16) {
    int s[8];
#pragma unroll
    for (int k = 0; k < 8; k++) s[k] = csr[j + 2 * k + half];
    uint2 u[8];
#pragma unroll
    for (int k = 0; k < 8; k++) u[k] = xwb2[(size_t)s[k] * 32 + cidx];
#pragma unroll
    for (int k = 0; k < 8; k++) {
      a0 += blo(u[k].x); a1 += bhi(u[k].x);
      a2 += blo(u[k].y); a3 += bhi(u[k].y);
    }
  }
  for (; j + 8 <= end; j += 8) {
    int s0 = csr[j + half], s1 = csr[j + 2 + half];
    int s2 = csr[j + 4 + half], s3 = csr[j + 6 + half];
    uint2 u0 = xwb2[(size_t)s0 * 32 + cidx];
    uint2 u1 = xwb2[(size_t)s1 * 32 + cidx];
    uint2 u2 = xwb2[(size_t)s2 * 32 + cidx];
    uint2 u3 = xwb2[(size_t)s3 * 32 + cidx];
    a0 += blo(u0.x); a1 += bhi(u0.x); a2 += blo(u0.y); a3 += bhi(u0.y);
    a0 += blo(u1.x); a1 += bhi(u1.x); a2 += blo(u1.y); a3 += bhi(u1.y);
    a0 += blo(u2.x); a1 += bhi(u2.x); a2 += blo(u2.y); a3 += bhi(u2.y);
    a0 += blo(u3.x); a1 += bhi(u3.x); a2 += blo(u3.y); a3 += bhi(u3.y);
  }
  for (; j < end; j += 2) {
    int jj = j + half;
    if (jj < end) {
      int s = csr[jj];
      uint2 u = xwb2[(size_t)s * 32 + cidx];
      a0 += blo(u.x); a1 += bhi(u.x); a2 += blo(u.y); a3 += bhi(u.y);
    }
  }

  a0 += __shfl_xor(a0, 32);
  a1 += __shfl_xor(a1, 32);
  a2 += __shfl_xor(a2, 32);
  a3 += __shfl_xor(a3, 32);

  if (half == 0) {
    const float4 bv = *(const float4*)&bias[cidx * 4];
    uint2 hu = hb2[(size_t)node * 32 + cidx];
    float r0 = fmaxf(blo(hu.x) + self * a0 + bv.x, 0.f);
    float r1 = fmaxf(bhi(hu.x) + self * a1 + bv.y, 0.f);
    float r2 = fmaxf(blo(hu.y) + self * a2 + bv.z, 0.f);
    float r3 = fmaxf(bhi(hu.y) + self * a3 + bv.w, 0.f);
    hb2[(size_t)node * 32 + cidx] = make_uint2(packb2(r0, r1), packb2(r2, r3));
    if (hout) *(float4*)&hout[(size_t)node * DH + cidx * 4] = make_float4(r0, r1, r2, r3);
  }
}

// ---------------- fused dual MLP head (128-row block, 32 rows/wave) ----------------

__global__ __launch_bounds__(256) void heads_kernel(
    const unsigned short* __restrict__ hb,
    const unsigned short* __restrict__ w1T_a, const float* __restrict__ b1_a,
    const float* __restrict__ w2_a, const float* __restrict__ b2_a,
    const unsigned short* __restrict__ w1T_b, const float* __restrict__ b1_b,
    const float* __restrict__ w2_b, const float* __restrict__ b2_b,
    float* __restrict__ out_a, float* __restrict__ out_b, int n) {
  const int t = threadIdx.x;
  const int lane = t & 63;
  const int w = t >> 6;
  const int lr = lane & 15, lg = lane >> 4;
  const int r_base = blockIdx.x * 128 + w * 32;

#pragma unroll
  for (int head = 0; head < 2; head++) {
    const unsigned short* W1T = head ? w1T_b : w1T_a;
    const float* b1 = head ? b1_b : b1_a;
    const float* w2 = head ? w2_b : w2_a;
    const float b2 = head ? b2_b[0] : b2_a[0];
    float* out = head ? out_b : out_a;

    f32x4 acc[2][8] = {};
#pragma unroll
    for (int kk = 0; kk < 4; kk++) {
      const int koff = kk * 32 + lg * 8;
      short8 a[2];
#pragma unroll
      for (int m = 0; m < 2; m++) {
        int row = r_base + m * 16 + lr;
        row = row < n ? row : n - 1;
        a[m] = *(const short8*)&hb[(size_t)row * DH + koff];
      }
#pragma unroll
      for (int nb = 0; nb < 8; nb++) {
        short8 b = *(const short8*)&W1T[(size_t)(nb * 16 + lr) * DH + koff];
#pragma unroll
        for (int m = 0; m < 2; m++)
          acc[m][nb] = __builtin_amdgcn_mfma_f32_16x16x32_bf16(a[m], b, acc[m][nb], 0, 0, 0);
      }
    }

    float b1v[8], w2v[8];
#pragma unroll
    for (int nb = 0; nb < 8; nb++) {
      b1v[nb] = b1[nb * 16 + lr];
      w2v[nb] = w2[nb * 16 + lr];
    }

#pragma unroll
    for (int m = 0; m < 2; m++) {
#pragma unroll
      for (int i = 0; i < 4; i++) {
        float s = 0.f;
#pragma unroll
        for (int nb = 0; nb < 8; nb++)
          s += fmaxf(acc[m][nb][i] + b1v[nb], 0.f) * w2v[nb];
        s += __shfl_xor(s, 1);
        s += __shfl_xor(s, 2);
        s += __shfl_xor(s, 4);
        s += __shfl_xor(s, 8);
        int row = r_base + m * 16 + lg * 4 + i;
        if (lr == 0 && row < n) out[row] = 1.f / (1.f + __expf(-(s + b2)));
      }
    }
  }
}

// ---------------- launch ----------------

extern "C" void kernel_launch(void* const* d_in, const int* in_sizes, int n_in,
                              void* d_out, int out_size, void* d_ws, size_t ws_size,
                              hipStream_t stream) {
  const float* x     = (const float*)d_in[0];
  const int*   ei    = (const int*)d_in[1];
  const float* w_in  = (const float*)d_in[2];
  const float* b_in  = (const float*)d_in[3];
  const float* w_gcn = (const float*)d_in[4];
  const float* b_gcn = (const float*)d_in[5];
  const float* w_nc1 = (const float*)d_in[6];
  const float* b_nc1 = (const float*)d_in[7];
  const float* w_nc2 = (const float*)d_in[8];
  const float* b_nc2 = (const float*)d_in[9];
  const float* w_oc1 = (const float*)d_in[10];
  const float* b_oc1 = (const float*)d_in[11];
  const float* w_oc2 = (const float*)d_in[12];
  const float* b_oc2 = (const float*)d_in[13];

  const int N = in_sizes[0] / 256;  // 50000
  const int E = in_sizes[1] / 2;    // 600000
  const int* erow = ei;
  const int* ecol = ei + E;

  float* out      = (float*)d_out;
  float* out_node = out;
  float* out_orig = out + N;
  float* out_err  = out + 2 * (size_t)N;
  float* h        = out + 6 * (size_t)N;  // final h written by last agg

  // workspace carve
  unsigned short* xwb = (unsigned short*)d_ws;            // N*128 bf16
  unsigned short* hb  = xwb + (size_t)N * DH;             // N*128 bf16
  unsigned short* w_inT  = hb + (size_t)N * DH;           // 128 x 256
  unsigned short* w_gcnT = w_inT + 128 * 256;             // 3 x 128 x 128
  unsigned short* w_nc1T = w_gcnT + 3 * 128 * 128;
  unsigned short* w_oc1T = w_nc1T + 128 * 128;
  float* dinv = (float*)(w_oc1T + 128 * 128);             // N
  int* cnt    = (int*)(dinv + N);                         // N
  int* rowptr = cnt + N;                                  // N+1
  int* bsum   = rowptr + N + 1;                           // 64
  int* rank   = bsum + 64;                                // E
  int* csr    = rank + E;                                 // E

  prep_kernel<<<(114688 + 5 * N + 255) / 256, 256, 0, stream>>>(
      w_in, w_gcn, w_nc1, w_oc1, w_inT, w_gcnT, w_nc1T, w_oc1T, cnt, out_err, N);

  const int gb = (N + 127) / 128;  // 391
  const int CB = 160, FB = 160;

  // fused: count+rank || input projection (hb = bf16(relu(x @ w_in + b_in)))
  count_ingemm_kernel<<<CB + gb, 256, 0, stream>>>(ecol, cnt, rank, E,
                                                   x, w_inT, b_in, hb, N, CB);

  const int nb1 = (N + 1023) / 1024;
  scan1_kernel<<<nb1, 1024, 0, stream>>>(cnt, rowptr, dinv, bsum, N);
  scan3_kernel<<<(N + 255) / 256, 256, 0, stream>>>(rowptr, bsum, N, nb1);

  // fused: CSR fill || layer-0 GEMM (xwb = dinv * (hb @ W0))
  fill_gemm_kernel<<<FB + gb, 256, 0, stream>>>(erow, ecol, rowptr, rank, csr, E,
                                                hb, w_gcnT, dinv, xwb, N, FB);
  agg_kernel<<<(N + 3) / 4, 256, 0, stream>>>((const uint2*)xwb, dinv, rowptr, csr,
                                              b_gcn, (uint2*)hb, nullptr, N);

  // layers 1,2
  for (int l = 1; l < 3; l++) {
    gemm_kernel<128, false, 0><<<gb, 256, 0, stream>>>(hb, w_gcnT + (size_t)l * DH * DH,
                                                       nullptr, dinv, xwb, N);
    agg_kernel<<<(N + 3) / 4, 256, 0, stream>>>((const uint2*)xwb, dinv, rowptr, csr,
                                                b_gcn + (size_t)l * DH, (uint2*)hb,
                                                l == 2 ? h : nullptr, N);
  }
  // fused heads
  heads_kernel<<<gb, 256, 0, stream>>>(hb, w_nc1T, b_nc1, w_nc2, b_nc2,
                                       w_oc1T, b_oc1, w_oc2, b_oc2,
                                       out_node, out_orig, N);
}